// Round 1
// baseline (2891.992 us; speedup 1.0000x reference)
//
#include <hip/hip_runtime.h>

#define DEV __device__ __forceinline__

DEV float fexp2(float x){ return __builtin_amdgcn_exp2f(x); }
DEV float frcp (float x){ return __builtin_amdgcn_rcpf(x); }

// sigmoid(x) = 1/(1+exp(-x));  exp(-x)=exp2(-x*log2e). Safe at extremes.
DEV float sigm(float x){
  float e = fexp2(x * -1.44269504088896341f);
  return frcp(1.0f + e);
}
// tanh(x) = sign(x) * (1-e)/(1+e), e = exp(-2|x|)  (e in (0,1], overflow-safe)
DEV float tanhx(float x){
  float ax = __builtin_fabsf(x);
  float e  = fexp2(ax * -2.88539008177792682f);
  float t  = (1.0f - e) * frcp(1.0f + e);
  return __builtin_copysignf(t, x);
}

// G=8 lanes per batch element. Lane k owns LSTM2 hidden units {2k, 2k+1}.
// After the xor-butterfly all-gather, register hall[m] holds h2[cu(m)] with
// cu(m) = 2*(k ^ (m>>1)) + (m&1); w_hh2 columns are loaded pre-permuted to match.
__global__ __launch_bounds__(256, 2)
void lstm3_kernel(const float* __restrict__ x,
                  const float* __restrict__ w_ih1, const float* __restrict__ w_hh1,
                  const float* __restrict__ b_ih1, const float* __restrict__ b_hh1,
                  const float* __restrict__ w_ih2, const float* __restrict__ w_hh2,
                  const float* __restrict__ b_ih2, const float* __restrict__ b_hh2,
                  const float* __restrict__ w_ih3, const float* __restrict__ w_hh3,
                  const float* __restrict__ b_ih3, const float* __restrict__ b_hh3,
                  const float* __restrict__ w_lin, const float* __restrict__ b_lin,
                  float* __restrict__ out, int T)
{
  const int gt = blockIdx.x * 256 + threadIdx.x;
  const int b  = gt >> 3;
  const int k  = gt & 7;

  // ---- LSTM1 weights (replicated in every lane)
  float w1x[8][2], w1h[8][2], bb1[8];
  #pragma unroll
  for (int r = 0; r < 8; ++r){
    w1x[r][0] = w_ih1[2*r]; w1x[r][1] = w_ih1[2*r+1];
    w1h[r][0] = w_hh1[2*r]; w1h[r][1] = w_hh1[2*r+1];
    bb1[r]    = b_ih1[r] + b_hh1[r];
  }

  // ---- LSTM2 weights: gate t in {i,f,g,o}, local unit j -> row 16t + 2k + j
  float w2x[4][2][2], w2h[4][2][16], bb2[4][2];
  #pragma unroll
  for (int t = 0; t < 4; ++t){
    #pragma unroll
    for (int j = 0; j < 2; ++j){
      const int r = 16*t + 2*k + j;
      w2x[t][j][0] = w_ih2[2*r]; w2x[t][j][1] = w_ih2[2*r+1];
      bb2[t][j]    = b_ih2[r] + b_hh2[r];
      #pragma unroll
      for (int m = 0; m < 16; ++m){
        const int cu = 2*(k ^ (m >> 1)) + (m & 1);   // permuted column
        w2h[t][j][m] = w_hh2[16*r + cu];
      }
    }
  }

  // ---- LSTM3: partial-dot columns for own units; tail replicated
  float w3p[4][2], bb3[4], wh3[4];
  #pragma unroll
  for (int r = 0; r < 4; ++r){
    w3p[r][0] = w_ih3[16*r + 2*k];
    w3p[r][1] = w_ih3[16*r + 2*k + 1];
    bb3[r]    = b_ih3[r] + b_hh3[r];
    wh3[r]    = w_hh3[r];
  }
  const float wl = w_lin[0], bl = b_lin[0];

  // ---- state
  float h1a = 0.f, h1b = 0.f, c1a = 0.f, c1b = 0.f;
  float c2o[2] = {0.f, 0.f};
  float hall[16];
  #pragma unroll
  for (int m = 0; m < 16; ++m) hall[m] = 0.f;
  float h3 = 0.f, c3 = 0.f;

  const float* xrow = x + (size_t)b * (size_t)(2*T);
  float*       orow = out + (size_t)b * (size_t)T;

  float4 pa = *(const float4*)(xrow);
  float4 pb = *(const float4*)(xrow + 4);

  const int NCH = T / 4;
  for (int ch = 0; ch < NCH; ++ch){
    const float4 ca = pa, cb = pb;
    const int no = (ch + 1 < NCH) ? (ch + 1) * 8 : 0;   // prefetch next chunk
    pa = *(const float4*)(xrow + no);
    pb = *(const float4*)(xrow + no + 4);

    float outv0, outv1, outv2, outv3;

    #pragma unroll
    for (int s = 0; s < 4; ++s){
      const float x0 = (s==0)?ca.x:(s==1)?ca.z:(s==2)?cb.x:cb.z;
      const float x1 = (s==0)?ca.y:(s==1)?ca.w:(s==2)?cb.y:cb.w;

      // ---------- LSTM1 (replicated) ----------
      float g1[8];
      #pragma unroll
      for (int r = 0; r < 8; ++r)
        g1[r] = fmaf(w1x[r][0], x0, fmaf(w1x[r][1], x1,
                fmaf(w1h[r][0], h1a, fmaf(w1h[r][1], h1b, bb1[r]))));
      {
        const float i0 = sigm(g1[0]),  i1 = sigm(g1[1]);
        const float f0 = sigm(g1[2]),  f1 = sigm(g1[3]);
        const float gA = tanhx(g1[4]), gB = tanhx(g1[5]);
        const float o0 = sigm(g1[6]),  o1 = sigm(g1[7]);
        c1a = fmaf(f0, c1a, i0 * gA);
        c1b = fmaf(f1, c1b, i1 * gB);
        h1a = o0 * tanhx(c1a);
        h1b = o1 * tanhx(c1b);
      }

      // ---------- LSTM2: own 8 gate rows ----------
      float pre[4][2];
      #pragma unroll
      for (int t = 0; t < 4; ++t){
        #pragma unroll
        for (int j = 0; j < 2; ++j){
          float acc = fmaf(w2x[t][j][0], h1a, fmaf(w2x[t][j][1], h1b, bb2[t][j]));
          #pragma unroll
          for (int m = 0; m < 16; ++m)
            acc = fmaf(w2h[t][j][m], hall[m], acc);
          pre[t][j] = acc;
        }
      }
      float h2o[2];
      #pragma unroll
      for (int j = 0; j < 2; ++j){
        const float ii = sigm(pre[0][j]);
        const float ff = sigm(pre[1][j]);
        const float gg = tanhx(pre[2][j]);
        const float oo = sigm(pre[3][j]);
        c2o[j] = fmaf(ff, c2o[j], ii * gg);
        h2o[j] = oo * tanhx(c2o[j]);
      }

      // ---------- all-gather h2 (xor butterfly; order matches weight perm) ----------
      hall[0] = h2o[0];
      hall[1] = h2o[1];
      hall[2] = __shfl_xor(h2o[0], 1, 64);
      hall[3] = __shfl_xor(h2o[1], 1, 64);
      #pragma unroll
      for (int m = 0; m < 4; ++m) hall[4 + m] = __shfl_xor(hall[m], 2, 64);
      #pragma unroll
      for (int m = 0; m < 8; ++m) hall[8 + m] = __shfl_xor(hall[m], 4, 64);

      // ---------- LSTM3: distributed dot + butterfly reduce ----------
      float p3[4];
      #pragma unroll
      for (int r = 0; r < 4; ++r)
        p3[r] = fmaf(w3p[r][0], h2o[0], w3p[r][1] * h2o[1]);
      #pragma unroll
      for (int r = 0; r < 4; ++r) p3[r] += __shfl_xor(p3[r], 1, 64);
      #pragma unroll
      for (int r = 0; r < 4; ++r) p3[r] += __shfl_xor(p3[r], 2, 64);
      #pragma unroll
      for (int r = 0; r < 4; ++r) p3[r] += __shfl_xor(p3[r], 4, 64);

      const float pre30 = fmaf(wh3[0], h3, p3[0] + bb3[0]);
      const float pre31 = fmaf(wh3[1], h3, p3[1] + bb3[1]);
      const float pre32 = fmaf(wh3[2], h3, p3[2] + bb3[2]);
      const float pre33 = fmaf(wh3[3], h3, p3[3] + bb3[3]);
      const float i3 = sigm(pre30), f3 = sigm(pre31);
      const float g3 = tanhx(pre32), o3 = sigm(pre33);
      c3 = fmaf(f3, c3, i3 * g3);
      h3 = o3 * tanhx(c3);

      const float ov = fmaf(wl, h3, bl);
      if      (s == 0) outv0 = ov;
      else if (s == 1) outv1 = ov;
      else if (s == 2) outv2 = ov;
      else             outv3 = ov;
    }

    // lanes 0..3 of the group write the 4 consecutive outputs
    float sel = outv0;
    sel = (k == 1) ? outv1 : sel;
    sel = (k == 2) ? outv2 : sel;
    sel = (k == 3) ? outv3 : sel;
    if (k < 4) orow[ch * 4 + k] = sel;
  }
}

extern "C" void kernel_launch(void* const* d_in, const int* in_sizes, int n_in,
                              void* d_out, int out_size, void* d_ws, size_t ws_size,
                              hipStream_t stream)
{
  const float* x     = (const float*)d_in[0];
  const float* w_ih1 = (const float*)d_in[1];
  const float* w_hh1 = (const float*)d_in[2];
  const float* b_ih1 = (const float*)d_in[3];
  const float* b_hh1 = (const float*)d_in[4];
  const float* w_ih2 = (const float*)d_in[5];
  const float* w_hh2 = (const float*)d_in[6];
  const float* b_ih2 = (const float*)d_in[7];
  const float* b_hh2 = (const float*)d_in[8];
  const float* w_ih3 = (const float*)d_in[9];
  const float* w_hh3 = (const float*)d_in[10];
  const float* b_ih3 = (const float*)d_in[11];
  const float* b_hh3 = (const float*)d_in[12];
  const float* w_lin = (const float*)d_in[13];
  const float* b_lin = (const float*)d_in[14];
  float* out = (float*)d_out;

  const int T = 2048;
  const int B = in_sizes[0] / (2 * T);     // 16384
  const int threads = B * 8;               // 8 lanes per batch element
  const int blocks  = threads / 256;       // 512

  lstm3_kernel<<<blocks, 256, 0, stream>>>(
      x, w_ih1, w_hh1, b_ih1, b_hh1,
      w_ih2, w_hh2, b_ih2, b_hh2,
      w_ih3, w_hh3, b_ih3, b_hh3,
      w_lin, b_lin, out, T);
}

// Round 2
// 1963.402 us; speedup vs baseline: 1.4729x; 1.4729x over previous
//
#include <hip/hip_runtime.h>

typedef _Float16 h2_t __attribute__((ext_vector_type(2)));

#define DEV __device__ __forceinline__

DEV float fexp2(float x){ return __builtin_amdgcn_exp2f(x); }
DEV float frcp (float x){ return __builtin_amdgcn_rcpf(x); }

// sigmoid via exp2+rcp; safe at +/-inf and on don't-care lanes.
DEV float sigm(float x){
  float e = fexp2(x * -1.44269504088896341f);
  return frcp(1.0f + e);
}

DEV unsigned packh2(float a, float b){
  h2_t h; h.x = (_Float16)a; h.y = (_Float16)b;   // v_cvt_f16_f32 (RNE) x2 + pack
  return __builtin_bit_cast(unsigned, h);
}

DEV float dot2u(h2_t w, unsigned hbits, float acc){
#if __has_builtin(__builtin_amdgcn_fdot2)
  return __builtin_amdgcn_fdot2(w, __builtin_bit_cast(h2_t, hbits), acc, false);
#else
  float r;
  asm("v_dot2_f32_f16 %0, %1, %2, %3" : "=v"(r) : "v"(w), "v"(hbits), "v"(acc));
  return r;
#endif
}

DEV float sxf(float v, int m){ return __shfl_xor(v, m, 64); }
DEV int   sxi(int v,   int m){ return __shfl_xor(v, m, 64); }

// G=8 lanes per sequence. Lane k owns LSTM2 units {2k,2k+1}; LSTM1 gate row k;
// LSTM3 gate row k&3. All tanh = 2*sigm(2x)-1 with the 2x folded into weights.
__global__ __launch_bounds__(256, 2)
void lstm3_kernel(const float* __restrict__ x,
                  const float* __restrict__ w_ih1, const float* __restrict__ w_hh1,
                  const float* __restrict__ b_ih1, const float* __restrict__ b_hh1,
                  const float* __restrict__ w_ih2, const float* __restrict__ w_hh2,
                  const float* __restrict__ b_ih2, const float* __restrict__ b_hh2,
                  const float* __restrict__ w_ih3, const float* __restrict__ w_hh3,
                  const float* __restrict__ b_ih3, const float* __restrict__ b_hh3,
                  const float* __restrict__ w_lin, const float* __restrict__ b_lin,
                  float* __restrict__ out, int T)
{
  const int gt = blockIdx.x * 256 + threadIdx.x;
  const int b  = gt >> 3;
  const int k  = gt & 7;

  // ---- LSTM1: lane k owns gate row k (rows: i0,i1,f0,f1,g0,g1,o0,o1)
  const float sc1 = (k == 4 || k == 5) ? 2.0f : 1.0f;     // g rows pre-scaled
  const float a1m = (k == 4 || k == 5) ? 2.0f : 1.0f;     // post-fix: g=2s-1
  const float a1a = (k == 4 || k == 5) ? -1.0f : 0.0f;
  const float w1x0 = w_ih1[2*k]   * sc1;
  const float w1x1 = w_ih1[2*k+1] * sc1;
  const float w1h0 = w_hh1[2*k]   * sc1;
  const float w1h1 = w_hh1[2*k+1] * sc1;
  const float bb1  = (b_ih1[k] + b_hh1[k]) * sc1;

  // ---- LSTM2: rows 16t+2k+j, t in {i,f,g,o}; hall pair m = units {2(k^m),2(k^m)+1}
  h2_t  w2xp[4][2];
  h2_t  w2hp[4][2][8];
  float bb2[4][2];
  #pragma unroll
  for (int t = 0; t < 4; ++t){
    const float sc = (t == 2) ? 2.0f : 1.0f;
    #pragma unroll
    for (int j = 0; j < 2; ++j){
      const int r = 16*t + 2*k + j;
      w2xp[t][j].x = (_Float16)(w_ih2[2*r]   * sc);
      w2xp[t][j].y = (_Float16)(w_ih2[2*r+1] * sc);
      bb2[t][j]    = (b_ih2[r] + b_hh2[r]) * sc;
      #pragma unroll
      for (int m = 0; m < 8; ++m){
        const int c0 = 2*(k ^ m);
        w2hp[t][j][m].x = (_Float16)(w_hh2[16*r + c0]     * sc);
        w2hp[t][j][m].y = (_Float16)(w_hh2[16*r + c0 + 1] * sc);
      }
    }
  }

  // ---- LSTM3: per-lane own row r3=k&3; p3 contributions from own columns for all rows
  const int   r3  = k & 3;
  const float sc3r = (r3 == 2) ? 2.0f : 1.0f;
  const float a3m  = (r3 == 2) ? 2.0f : 1.0f;
  const float a3a  = (r3 == 2) ? -1.0f : 0.0f;
  float w3c[4][2];
  #pragma unroll
  for (int r = 0; r < 4; ++r){
    const float sc = (r == 2) ? 2.0f : 1.0f;
    w3c[r][0] = w_ih3[16*r + 2*k]     * sc;
    w3c[r][1] = w_ih3[16*r + 2*k + 1] * sc;
  }
  const float bb3o = (b_ih3[r3] + b_hh3[r3]) * sc3r;
  const float wh3o = w_hh3[r3] * sc3r;
  const float wl = w_lin[0], bl = b_lin[0];

  // ---- state
  float h1a = 0.f, h1b = 0.f, c1 = 0.f;
  float c2o0 = 0.f, c2o1 = 0.f;
  unsigned hp[8];
  #pragma unroll
  for (int m = 0; m < 8; ++m) hp[m] = 0u;
  float h3 = 0.f, c3 = 0.f;

  const float* xrow = x + (size_t)b * (size_t)(2*T);
  float*       orow = out + (size_t)b * (size_t)T;

  float4 pa = *(const float4*)(xrow);
  float4 pb = *(const float4*)(xrow + 4);

  const int NCH = T / 4;
  for (int ch = 0; ch < NCH; ++ch){
    const float4 ca = pa, cb = pb;
    const int no = (ch + 1 < NCH) ? (ch + 1) * 8 : 0;
    pa = *(const float4*)(xrow + no);
    pb = *(const float4*)(xrow + no + 4);

    float outv0, outv1, outv2, outv3;

    #pragma unroll
    for (int s = 0; s < 4; ++s){
      const float x0 = (s==0)?ca.x:(s==1)?ca.z:(s==2)?cb.x:cb.z;
      const float x1 = (s==0)?ca.y:(s==1)?ca.w:(s==2)?cb.y:cb.w;

      // ---- LSTM2 hall part first (depends only on previous-step hp) ----
      float pre[4][2];
      #pragma unroll
      for (int t = 0; t < 4; ++t)
        #pragma unroll
        for (int j = 0; j < 2; ++j){
          float acc = bb2[t][j];
          #pragma unroll
          for (int m = 0; m < 8; ++m) acc = dot2u(w2hp[t][j][m], hp[m], acc);
          pre[t][j] = acc;
        }

      // ---- LSTM1 (distributed: 1 gate row per lane) ----
      const float g1 = fmaf(w1x0, x0, fmaf(w1x1, x1,
                       fmaf(w1h0, h1a, fmaf(w1h1, h1b, bb1))));
      const float z1 = fmaf(sigm(g1), a1m, a1a);          // i/f/o: s ; g: 2s-1
      const float t1 = sxf(z1, 4);                        // lane0: gA, lane2: o0 ...
      const float m1 = z1 * t1;                           // lanes 0,1(,4,5): i*g
      const float u1 = sxf(z1, 2);                        // lanes0,1: f ; 4,5: o
      const float v1 = sxf(t1, 2);                        // lanes0,1: o ; 4,5: f
      const float fv = (k & 4) ? v1 : u1;
      const float ov = (k & 4) ? u1 : v1;
      c1 = fmaf(fv, c1, m1);                              // c1a on 0,4; c1b on 1,5
      const float th1 = fmaf(2.f, sigm(c1 + c1), -1.f);   // tanh(c1)
      const float hh  = ov * th1;
      h1a = __shfl(hh, 0, 8);
      h1b = __shfl(hh, 1, 8);
      const unsigned h1p = packh2(h1a, h1b);

      // ---- LSTM2: add input part, activations ----
      float h2o0, h2o1;
      {
        const float p_i0 = dot2u(w2xp[0][0], h1p, pre[0][0]);
        const float p_f0 = dot2u(w2xp[1][0], h1p, pre[1][0]);
        const float p_g0 = dot2u(w2xp[2][0], h1p, pre[2][0]);
        const float p_o0 = dot2u(w2xp[3][0], h1p, pre[3][0]);
        const float ii = sigm(p_i0);
        const float ff = sigm(p_f0);
        const float gg = fmaf(2.f, sigm(p_g0), -1.f);
        const float oo = sigm(p_o0);
        c2o0 = fmaf(ff, c2o0, ii * gg);
        h2o0 = oo * fmaf(2.f, sigm(c2o0 + c2o0), -1.f);
      }
      {
        const float p_i1 = dot2u(w2xp[0][1], h1p, pre[0][1]);
        const float p_f1 = dot2u(w2xp[1][1], h1p, pre[1][1]);
        const float p_g1 = dot2u(w2xp[2][1], h1p, pre[2][1]);
        const float p_o1 = dot2u(w2xp[3][1], h1p, pre[3][1]);
        const float ii = sigm(p_i1);
        const float ff = sigm(p_f1);
        const float gg = fmaf(2.f, sigm(p_g1), -1.f);
        const float oo = sigm(p_o1);
        c2o1 = fmaf(ff, c2o1, ii * gg);
        h2o1 = oo * fmaf(2.f, sigm(c2o1 + c2o1), -1.f);
      }

      // ---- all-gather h2 as packed f16 pairs (7 shuffles) ----
      hp[0] = packh2(h2o0, h2o1);
      hp[1] = (unsigned)sxi((int)hp[0], 1);
      hp[2] = (unsigned)sxi((int)hp[0], 2);
      hp[3] = (unsigned)sxi((int)hp[1], 2);
      hp[4] = (unsigned)sxi((int)hp[0], 4);
      hp[5] = (unsigned)sxi((int)hp[1], 4);
      hp[6] = (unsigned)sxi((int)hp[2], 4);
      hp[7] = (unsigned)sxi((int)hp[3], 4);

      // ---- LSTM3: own-column partials for 4 rows, reduce-scatter to own row ----
      float p0 = fmaf(w3c[0][0], h2o0, w3c[0][1] * h2o1);
      float p1 = fmaf(w3c[1][0], h2o0, w3c[1][1] * h2o1);
      float p2 = fmaf(w3c[2][0], h2o0, w3c[2][1] * h2o1);
      float p3 = fmaf(w3c[3][0], h2o0, w3c[3][1] * h2o1);
      p0 += sxf(p0, 4); p1 += sxf(p1, 4); p2 += sxf(p2, 4); p3 += sxf(p3, 4);
      const float sa = (k & 2) ? p0 : p2;
      const float sb = (k & 2) ? p1 : p3;
      const float ra = sxf(sa, 2);
      const float rb = sxf(sb, 2);
      const float qa = ((k & 2) ? p2 : p0) + ra;   // rows {0,2} halves
      const float qb = ((k & 2) ? p3 : p1) + rb;   // rows {1,3} halves
      const float sc_ = (k & 1) ? qa : qb;
      const float rc  = sxf(sc_, 1);
      const float q   = ((k & 1) ? qb : qa) + rc;  // full row (k&3) sum

      const float pre3 = q + fmaf(wh3o, h3, bb3o);
      const float z3 = fmaf(sigm(pre3), a3m, a3a); // lane r3: i,f,g,o value
      const float t3 = sxf(z3, 2);                 // lane0: g ; lane1: o
      const float m3 = z3 * t3;                    // lane0: i*g
      const float u3 = sxf(z3, 1);                 // lane0: f
      const float o3 = sxf(t3, 1);                 // lane0: o
      c3 = fmaf(u3, c3, m3);                       // valid on lanes 0,4
      const float th3 = fmaf(2.f, sigm(c3 + c3), -1.f);
      const float h3v = o3 * th3;
      h3 = __shfl(h3v, 0, 8);

      const float oval = fmaf(wl, h3, bl);
      if      (s == 0) outv0 = oval;
      else if (s == 1) outv1 = oval;
      else if (s == 2) outv2 = oval;
      else             outv3 = oval;
    }

    float sel = outv0;
    sel = (k == 1) ? outv1 : sel;
    sel = (k == 2) ? outv2 : sel;
    sel = (k == 3) ? outv3 : sel;
    if (k < 4) orow[ch * 4 + k] = sel;
  }
}

extern "C" void kernel_launch(void* const* d_in, const int* in_sizes, int n_in,
                              void* d_out, int out_size, void* d_ws, size_t ws_size,
                              hipStream_t stream)
{
  const float* x     = (const float*)d_in[0];
  const float* w_ih1 = (const float*)d_in[1];
  const float* w_hh1 = (const float*)d_in[2];
  const float* b_ih1 = (const float*)d_in[3];
  const float* b_hh1 = (const float*)d_in[4];
  const float* w_ih2 = (const float*)d_in[5];
  const float* w_hh2 = (const float*)d_in[6];
  const float* b_ih2 = (const float*)d_in[7];
  const float* b_hh2 = (const float*)d_in[8];
  const float* w_ih3 = (const float*)d_in[9];
  const float* w_hh3 = (const float*)d_in[10];
  const float* b_ih3 = (const float*)d_in[11];
  const float* b_hh3 = (const float*)d_in[12];
  const float* w_lin = (const float*)d_in[13];
  const float* b_lin = (const float*)d_in[14];
  float* out = (float*)d_out;

  const int T = 2048;
  const int B = in_sizes[0] / (2 * T);     // 16384
  const int threads = B * 8;
  const int blocks  = threads / 256;       // 512

  lstm3_kernel<<<blocks, 256, 0, stream>>>(
      x, w_ih1, w_hh1, b_ih1, b_hh1,
      w_ih2, w_hh2, b_ih2, b_hh2,
      w_ih3, w_hh3, b_ih3, b_hh3,
      w_lin, b_lin, out, T);
}

// Round 8
// 1562.912 us; speedup vs baseline: 1.8504x; 1.2562x over previous
//
#include <hip/hip_runtime.h>

typedef _Float16 f16x8 __attribute__((ext_vector_type(8)));
typedef float    f32x4 __attribute__((ext_vector_type(4)));
typedef unsigned u32x4 __attribute__((ext_vector_type(4)));

#define DEV __device__ __forceinline__

DEV float fexp2(float x){ return __builtin_amdgcn_exp2f(x); }
DEV float frcp (float x){ return __builtin_amdgcn_rcpf(x); }
// sigmoid; safe at extremes (exp2->inf -> rcp->0)
DEV float sigm(float x){ return frcp(1.0f + fexp2(x * -1.44269504088896341f)); }

// cross-lane via __shfl_xor ONLY (validated R1/R2; permlane_swap helpers from
// R4-R7 are the prime suspect for the persistent ~2-5e-2 bounded error).
DEV float shx(float v, int m){ return __shfl_xor(v, m, 64); }

// RNE f16 pack
DEV unsigned pkrne(float a, float b){
  unsigned short ha = __builtin_bit_cast(unsigned short, (_Float16)a);
  unsigned short hb = __builtin_bit_cast(unsigned short, (_Float16)b);
  return (unsigned)ha | ((unsigned)hb << 16);
}

// 16 seqs per wave. Lane l: seq-col n = l&15, group g = l>>4 (16-lane rows r0..r3).
// LSTM2 h2-recurrence via 4x mfma_f32_16x16x32_f16 using ONLY the first K-half
// (slots e<4, same (g,e)->k labeling for A and B; contraction is invariant to
// any shared relabeling). All e>=4 slots are ZERO in both A and B. The
// W_ih2*h1 term enters through the MFMA C operand in f32 (exact).
// D: col=n, row=4g+j (unit 4g+j). Lane packs its own 4 h2 units back as next
// step's B slots e=0..3 — no cross-lane redistribution needed.
__global__ __launch_bounds__(256, 1)
void lstm3_kernel(const float* __restrict__ x,
                  const float* __restrict__ w_ih1, const float* __restrict__ w_hh1,
                  const float* __restrict__ b_ih1, const float* __restrict__ b_hh1,
                  const float* __restrict__ w_ih2, const float* __restrict__ w_hh2,
                  const float* __restrict__ b_ih2, const float* __restrict__ b_hh2,
                  const float* __restrict__ w_ih3, const float* __restrict__ w_hh3,
                  const float* __restrict__ b_ih3, const float* __restrict__ b_hh3,
                  const float* __restrict__ w_lin, const float* __restrict__ b_lin,
                  float* __restrict__ out, int T)
{
  const int tid = threadIdx.x;
  const int l   = tid & 63;
  const int n   = l & 15;          // seq column
  const int g   = l >> 4;          // group/row 0..3
  const int wv  = tid >> 6;        // wave in block
  const int seq = 16 * (blockIdx.x * 4 + wv) + n;

  const bool isg0 = (g == 0), isg1 = (g == 1), isg2 = (g == 2);

  // ---------------- LSTM1 per-lane: rows g (i0,i1,f0,f1) and 4+g (g0,g1,o0,o1) ----------------
  const int rA = g, rB = 4 + g;
  const float scB = (g < 2) ? 2.0f : 1.0f;          // rows 4,5 are g-gate: tanh=2*sigm(2x)-1
  const float m1  = (g < 2) ? 2.0f : 1.0f;
  const float a1  = (g < 2) ? -1.0f : 0.0f;
  const float w1ax = w_ih1[2*rA],      w1ay = w_ih1[2*rA+1];
  const float w1ah0 = w_hh1[2*rA],     w1ah1 = w_hh1[2*rA+1];
  const float bbA  = b_ih1[rA] + b_hh1[rA];
  const float w1bx = w_ih1[2*rB]*scB,  w1by = w_ih1[2*rB+1]*scB;
  const float w1bh0 = w_hh1[2*rB]*scB, w1bh1 = w_hh1[2*rB+1]*scB;
  const float bbB  = (b_ih1[rB] + b_hh1[rB]) * scB;

  // ---------------- LSTM2: A fragments (h2 weights, first K-half only) ----------------
  f16x8 af[4];
  f32x4 cb[4];         // bias part of C
  float wx2[4][4][2];  // per-lane w_ih2 for OWN D-rows 16t+4g+j (f32, exact)
  #pragma unroll
  for (int t = 0; t < 4; ++t){
    const float sc = (t == 2) ? 2.0f : 1.0f;        // g-gate tile pre-scaled
    #pragma unroll
    for (int e = 0; e < 8; ++e){
      float v = 0.0f;
      if (e < 4) v = w_hh2[(16*t + n)*16 + (4*g + e)];
      af[t][e] = (_Float16)(v * sc);
    }
    #pragma unroll
    for (int j = 0; j < 4; ++j){
      const int r = 16*t + 4*g + j;                 // own D-row gate index
      cb[t][j]     = (b_ih2[r] + b_hh2[r]) * sc;
      wx2[t][j][0] = w_ih2[2*r]     * sc;
      wx2[t][j][1] = w_ih2[2*r + 1] * sc;
    }
  }

  // ---------------- LSTM3 per-lane ----------------
  float w3c[4][4];
  #pragma unroll
  for (int r = 0; r < 4; ++r){
    const float sc = (r == 2) ? 2.0f : 1.0f;
    #pragma unroll
    for (int j = 0; j < 4; ++j) w3c[r][j] = w_ih3[16*r + 4*g + j] * sc;
  }
  const float sc3 = (g == 2) ? 2.0f : 1.0f;
  const float m3  = (g == 2) ? 2.0f : 1.0f;
  const float a3  = (g == 2) ? -1.0f : 0.0f;
  const float wh3own = w_hh3[g] * sc3;
  const float bb3own = (b_ih3[g] + b_hh3[g]) * sc3;
  const float wl = w_lin[0], bl = b_lin[0];

  // ---------------- state ----------------
  float c1 = 0.f, c3 = 0.f;
  float c2[4] = {0.f, 0.f, 0.f, 0.f};
  float h1a_all = 0.f, h1b_all = 0.f, h3_all = 0.f;
  unsigned pAu = 0u, pBu = 0u;     // packed f16 h2 (own 4 units) from previous step

  const float* xrow = x + (size_t)seq * (size_t)(2*T);
  float*       orow = out + (size_t)seq * (size_t)T;

  float4 pa = *(const float4*)(xrow);
  float4 pb = *(const float4*)(xrow + 4);

  const int NCH = T / 4;
  for (int ch = 0; ch < NCH; ++ch){
    const float4 ca = pa, cbv = pb;
    const int no = (ch + 1 < NCH) ? (ch + 1) * 8 : 0;
    pa = *(const float4*)(xrow + no);
    pb = *(const float4*)(xrow + no + 4);

    float outv0, outv1, outv2, outv3;

    #pragma unroll
    for (int s = 0; s < 4; ++s){
      const float x0 = (s==0)?ca.x:(s==1)?ca.z:(s==2)?cbv.x:cbv.z;
      const float x1 = (s==0)?ca.y:(s==1)?ca.w:(s==2)?cbv.y:cbv.w;

      // ---------- LSTM1 (2 gate rows per lane, 4 lanes per seq) ----------
      const float gA = fmaf(w1ax, x0, fmaf(w1ay, x1,
                       fmaf(w1ah0, h1a_all, fmaf(w1ah1, h1b_all, bbA))));
      const float gB = fmaf(w1bx, x0, fmaf(w1by, x1,
                       fmaf(w1bh0, h1a_all, fmaf(w1bh1, h1b_all, bbB))));
      const float zA = sigm(gA);                    // r0:i0 r1:i1 r2:f0 r3:f1
      const float zB = fmaf(sigm(gB), m1, a1);      // r0:g0 r1:g1 r2:o0 r3:o1
      const float ig1 = zA * zB;                    // r0: i0*g0, r1: i1*g1
      const float fm = shx(zA, 32);                 // r0<-f0, r1<-f1
      c1 = fmaf(fm, c1, ig1);                       // r0: c1a, r1: c1b
      const float th1 = fmaf(2.f, sigm(c1 + c1), -1.f);
      const float om = shx(zB, 32);                 // r0<-o0, r1<-o1
      const float h1v = om * th1;                   // r0: h1a, r1: h1b
      // broadcast h1a,h1b to all 4 rows (column-preserving)
      const float t16 = shx(h1v, 16);               // r0<-h1b, r1<-h1a
      const float a_c = (g & 1) ? t16 : h1v;        // rows 0,1: h1a
      const float b_c = (g & 1) ? h1v : t16;        // rows 0,1: h1b
      const float a32 = shx(a_c, 32);
      const float b32 = shx(b_c, 32);
      h1a_all = (g & 2) ? a32 : a_c;                // all rows: h1a (f32)
      h1b_all = (g & 2) ? b32 : b_c;                // all rows: h1b (f32)

      // ---------- LSTM2: C = bias + W_ih2*h1 (f32 exact), then 4 MFMA ----------
      f32x4 cc0, cc1, cc2, cc3;
      #pragma unroll
      for (int j = 0; j < 4; ++j){
        cc0[j] = fmaf(wx2[0][j][0], h1a_all, fmaf(wx2[0][j][1], h1b_all, cb[0][j]));
        cc1[j] = fmaf(wx2[1][j][0], h1a_all, fmaf(wx2[1][j][1], h1b_all, cb[1][j]));
        cc2[j] = fmaf(wx2[2][j][0], h1a_all, fmaf(wx2[2][j][1], h1b_all, cb[2][j]));
        cc3[j] = fmaf(wx2[3][j][0], h1a_all, fmaf(wx2[3][j][1], h1b_all, cb[3][j]));
      }
      u32x4 bu; bu[0] = pAu; bu[1] = pBu; bu[2] = 0u; bu[3] = 0u;
      const f16x8 bv = __builtin_bit_cast(f16x8, bu);
      const f32x4 d0 = __builtin_amdgcn_mfma_f32_16x16x32_f16(af[0], bv, cc0, 0, 0, 0);
      const f32x4 d1 = __builtin_amdgcn_mfma_f32_16x16x32_f16(af[1], bv, cc1, 0, 0, 0);
      const f32x4 d2 = __builtin_amdgcn_mfma_f32_16x16x32_f16(af[2], bv, cc2, 0, 0, 0);
      const f32x4 d3 = __builtin_amdgcn_mfma_f32_16x16x32_f16(af[3], bv, cc3, 0, 0, 0);

      // ---------- LSTM2 activations + cell (lane-local, 4 units) ----------
      float h2l[4];
      #pragma unroll
      for (int j = 0; j < 4; ++j){
        const float ii = sigm(d0[j]);
        const float ff = sigm(d1[j]);
        const float gg = fmaf(2.f, sigm(d2[j]), -1.f);
        const float oo = sigm(d3[j]);
        c2[j] = fmaf(ff, c2[j], ii * gg);
        const float th = fmaf(2.f, sigm(c2[j] + c2[j]), -1.f);
        h2l[j] = oo * th;
      }
      pAu = pkrne(h2l[0], h2l[1]);
      pBu = pkrne(h2l[2], h2l[3]);

      // ---------- LSTM3: partial dots + shfl_xor tree (full sums on all lanes) ----------
      float p0 = fmaf(w3c[0][0], h2l[0], fmaf(w3c[0][1], h2l[1], fmaf(w3c[0][2], h2l[2], w3c[0][3]*h2l[3])));
      float p1 = fmaf(w3c[1][0], h2l[0], fmaf(w3c[1][1], h2l[1], fmaf(w3c[1][2], h2l[2], w3c[1][3]*h2l[3])));
      float p2 = fmaf(w3c[2][0], h2l[0], fmaf(w3c[2][1], h2l[1], fmaf(w3c[2][2], h2l[2], w3c[2][3]*h2l[3])));
      float p3 = fmaf(w3c[3][0], h2l[0], fmaf(w3c[3][1], h2l[1], fmaf(w3c[3][2], h2l[2], w3c[3][3]*h2l[3])));
      p0 += shx(p0, 32); p0 += shx(p0, 16);   // full row-0 sum, every lane
      p1 += shx(p1, 32); p1 += shx(p1, 16);
      p2 += shx(p2, 32); p2 += shx(p2, 16);
      p3 += shx(p3, 32); p3 += shx(p3, 16);
      float P = isg0 ? p0 : (isg1 ? p1 : (isg2 ? p2 : p3));
      P = fmaf(wh3own, h3_all, P + bb3own);
      const float z  = fmaf(sigm(P), m3, a3);       // r0:i r1:f r2:g r3:o
      const float gv = shx(z, 32);                  // r0<-g-val, r1<-o
      const float ig3 = z * gv;                     // r0: i*g
      const float fv = shx(z, 16);                  // r0<-f
      c3 = fmaf(fv, c3, ig3);                       // r0: c3
      const float th3 = fmaf(2.f, sigm(c3 + c3), -1.f);
      const float ov3 = shx(gv, 16);                // r0<-o
      const float h3v = ov3 * th3;                  // r0: h3
      // broadcast h3 to all rows
      const float u16 = shx(h3v, 16);
      const float selh = (g & 1) ? u16 : h3v;       // rows 0,1: h3
      const float u32v = shx(selh, 32);
      h3_all = (g & 2) ? u32v : selh;               // all rows: h3
      const float yv = fmaf(wl, h3_all, bl);

      if      (s == 0) outv0 = yv;
      else if (s == 1) outv1 = yv;
      else if (s == 2) outv2 = yv;
      else             outv3 = yv;
    }

    if (g == 0){
      float4 o4; o4.x = outv0; o4.y = outv1; o4.z = outv2; o4.w = outv3;
      *(float4*)(orow + ch * 4) = o4;
    }
  }
}

extern "C" void kernel_launch(void* const* d_in, const int* in_sizes, int n_in,
                              void* d_out, int out_size, void* d_ws, size_t ws_size,
                              hipStream_t stream)
{
  const float* x     = (const float*)d_in[0];
  const float* w_ih1 = (const float*)d_in[1];
  const float* w_hh1 = (const float*)d_in[2];
  const float* b_ih1 = (const float*)d_in[3];
  const float* b_hh1 = (const float*)d_in[4];
  const float* w_ih2 = (const float*)d_in[5];
  const float* w_hh2 = (const float*)d_in[6];
  const float* b_ih2 = (const float*)d_in[7];
  const float* b_hh2 = (const float*)d_in[8];
  const float* w_ih3 = (const float*)d_in[9];
  const float* w_hh3 = (const float*)d_in[10];
  const float* b_ih3 = (const float*)d_in[11];
  const float* b_hh3 = (const float*)d_in[12];
  const float* w_lin = (const float*)d_in[13];
  const float* b_lin = (const float*)d_in[14];
  float* out = (float*)d_out;

  const int T = 2048;
  const int B = in_sizes[0] / (2 * T);     // 16384
  const int waves   = B / 16;              // 1024 (16 seqs per wave)
  const int blocks  = waves / 4;           // 256 blocks of 256 threads

  lstm3_kernel<<<blocks, 256, 0, stream>>>(
      x, w_ih1, w_hh1, b_ih1, b_hh1,
      w_ih2, w_hh2, b_ih2, b_hh2,
      w_ih3, w_hh3, b_ih3, b_hh3,
      w_lin, b_lin, out, T);
}

// Round 9
// 1209.319 us; speedup vs baseline: 2.3914x; 1.2924x over previous
//
#include <hip/hip_runtime.h>

typedef _Float16 f16x8 __attribute__((ext_vector_type(8)));
typedef float    f32x4 __attribute__((ext_vector_type(4)));
typedef unsigned u32x4 __attribute__((ext_vector_type(4)));

#define DEV __device__ __forceinline__

DEV float fexp2(float x){ return __builtin_amdgcn_exp2f(x); }
DEV float frcp (float x){ return __builtin_amdgcn_rcpf(x); }
// sigmoid; safe at extremes (exp2->inf -> rcp->0)
DEV float sigm(float x){ return frcp(1.0f + fexp2(x * -1.44269504088896341f)); }

// cross-lane via __shfl_xor ONLY (validated R8; permlane_swap semantics were
// the R4-R7 bug).
DEV float shx(float v, int m){ return __shfl_xor(v, m, 64); }

// RNE f16 pack
DEV unsigned pkrne(float a, float b){
  unsigned short ha = __builtin_bit_cast(unsigned short, (_Float16)a);
  unsigned short hb = __builtin_bit_cast(unsigned short, (_Float16)b);
  return (unsigned)ha | ((unsigned)hb << 16);
}

// 16 seqs per wave. Lane l: seq-col n = l&15, group g = l>>4 (rows r0..r3).
// All MFMA A/B operands use ONLY first-half slots e<4 with the shared labeling
// k = 4g+e (A<->B pairing empirically validated by R7/R8 pass); e>=4 zero both
// sides. Three MFMA uses per step:
//   (1) gates_pre = mfma(A_hh2, B_h2prev, bias)      -- issues at step top
//   (2) gates     = mfma(A_ih2, B_h1,     gates_pre) -- h1 in g0 slots e0/e1
//   (3) pre3      = mfma(A_ih3, B_h2new,  bias3)     -- w_ih3 row r at A-row 4r
// D: col=n, rows 4g+j.
__global__ __launch_bounds__(256, 1)
void lstm3_kernel(const float* __restrict__ x,
                  const float* __restrict__ w_ih1, const float* __restrict__ w_hh1,
                  const float* __restrict__ b_ih1, const float* __restrict__ b_hh1,
                  const float* __restrict__ w_ih2, const float* __restrict__ w_hh2,
                  const float* __restrict__ b_ih2, const float* __restrict__ b_hh2,
                  const float* __restrict__ w_ih3, const float* __restrict__ w_hh3,
                  const float* __restrict__ b_ih3, const float* __restrict__ b_hh3,
                  const float* __restrict__ w_lin, const float* __restrict__ b_lin,
                  float* __restrict__ out, int T)
{
  const int tid = threadIdx.x;
  const int l   = tid & 63;
  const int n   = l & 15;          // seq column
  const int g   = l >> 4;          // group/row 0..3
  const int wv  = tid >> 6;        // wave in block
  const int seq = 16 * (blockIdx.x * 4 + wv) + n;

  // ---------------- LSTM1 per-lane: rows g (i0,i1,f0,f1) and 4+g (g0,g1,o0,o1) ----------------
  const int rA = g, rB = 4 + g;
  const float scB = (g < 2) ? 2.0f : 1.0f;          // rows 4,5 are g-gate: tanh=2*sigm(2x)-1
  const float m1  = (g < 2) ? 2.0f : 1.0f;
  const float a1  = (g < 2) ? -1.0f : 0.0f;
  const float w1ax = w_ih1[2*rA],      w1ay = w_ih1[2*rA+1];
  const float w1ah0 = w_hh1[2*rA],     w1ah1 = w_hh1[2*rA+1];
  const float bbA  = b_ih1[rA] + b_hh1[rA];
  const float w1bx = w_ih1[2*rB]*scB,  w1by = w_ih1[2*rB+1]*scB;
  const float w1bh0 = w_hh1[2*rB]*scB, w1bh1 = w_hh1[2*rB+1]*scB;
  const float bbB  = (b_ih1[rB] + b_hh1[rB]) * scB;

  // ---------------- LSTM2: A fragments ----------------
  f16x8 af[4];   // w_hh2 (h2 recurrence), slots e<4 = columns 4g+e
  f16x8 a2f[4];  // w_ih2 (h1 injection), g0 lanes slots e0/e1 only
  f32x4 cb[4];   // bias C
  #pragma unroll
  for (int t = 0; t < 4; ++t){
    const float sc = (t == 2) ? 2.0f : 1.0f;        // g-gate tile pre-scaled
    #pragma unroll
    for (int e = 0; e < 8; ++e){
      float v = 0.0f;
      if (e < 4) v = w_hh2[(16*t + n)*16 + (4*g + e)];
      af[t][e] = (_Float16)(v * sc);
      float v2 = 0.0f;
      if (g == 0 && e < 2) v2 = w_ih2[(16*t + n)*2 + e];
      a2f[t][e] = (_Float16)(v2 * sc);
    }
    #pragma unroll
    for (int j = 0; j < 4; ++j){
      const int r = 16*t + 4*g + j;
      cb[t][j] = (b_ih2[r] + b_hh2[r]) * sc;
    }
  }

  // ---------------- LSTM3: A fragment (w_ih3 gate r at A-row 4r) ----------------
  f16x8 a3f;
  #pragma unroll
  for (int e = 0; e < 8; ++e){
    float v = 0.0f;
    if ((n & 3) == 0 && e < 4){
      const int r = n >> 2;
      v = w_ih3[16*r + 4*g + e] * ((r == 2) ? 2.0f : 1.0f);
    }
    a3f[e] = (_Float16)v;
  }
  const float sc3 = (g == 2) ? 2.0f : 1.0f;
  const float m3  = (g == 2) ? 2.0f : 1.0f;
  const float a3  = (g == 2) ? -1.0f : 0.0f;
  const float wh3own = w_hh3[g] * sc3;
  const float bb3own = (b_ih3[g] + b_hh3[g]) * sc3;
  f32x4 c3v; c3v[0] = bb3own; c3v[1] = 0.f; c3v[2] = 0.f; c3v[3] = 0.f;
  const float wl = w_lin[0], bl = b_lin[0];

  // ---------------- state ----------------
  float c1 = 0.f, c3 = 0.f;
  float c2[4] = {0.f, 0.f, 0.f, 0.f};
  float h1a_all = 0.f, h1b_all = 0.f, h3_all = 0.f;
  unsigned pAu = 0u, pBu = 0u;     // packed f16 h2 (own 4 units) from previous step

  const float* xrow = x + (size_t)seq * (size_t)(2*T);
  float*       orow = out + (size_t)seq * (size_t)T;

  float4 pa = *(const float4*)(xrow);
  float4 pb = *(const float4*)(xrow + 4);

  float o0 = 0.f, o1 = 0.f, o2 = 0.f, o3 = 0.f;   // 4-step output buffer (per group)

  const int NCH = T / 4;
  for (int ch = 0; ch < NCH; ++ch){
    const float4 ca = pa, cbv = pb;
    const int no = (ch + 1 < NCH) ? (ch + 1) * 8 : 0;
    pa = *(const float4*)(xrow + no);
    pb = *(const float4*)(xrow + no + 4);

    const bool cap = (g == (ch & 3));   // which group captures this chunk's outputs

    #pragma unroll
    for (int s = 0; s < 4; ++s){
      const float x0 = (s==0)?ca.x:(s==1)?ca.z:(s==2)?cbv.x:cbv.z;
      const float x1 = (s==0)?ca.y:(s==1)?ca.w:(s==2)?cbv.y:cbv.w;

      // ---------- (1) h2-recurrence MFMA: depends only on prev h2, issue first ----------
      u32x4 bu; bu[0] = pAu; bu[1] = pBu; bu[2] = 0u; bu[3] = 0u;
      const f16x8 bv = __builtin_bit_cast(f16x8, bu);
      f32x4 d0 = __builtin_amdgcn_mfma_f32_16x16x32_f16(af[0], bv, cb[0], 0, 0, 0);
      f32x4 d1 = __builtin_amdgcn_mfma_f32_16x16x32_f16(af[1], bv, cb[1], 0, 0, 0);
      f32x4 d2 = __builtin_amdgcn_mfma_f32_16x16x32_f16(af[2], bv, cb[2], 0, 0, 0);
      f32x4 d3 = __builtin_amdgcn_mfma_f32_16x16x32_f16(af[3], bv, cb[3], 0, 0, 0);

      // ---------- LSTM1 (2 gate rows per lane, 4 lanes per seq) ----------
      const float gA = fmaf(w1ax, x0, fmaf(w1ay, x1,
                       fmaf(w1ah0, h1a_all, fmaf(w1ah1, h1b_all, bbA))));
      const float gB = fmaf(w1bx, x0, fmaf(w1by, x1,
                       fmaf(w1bh0, h1a_all, fmaf(w1bh1, h1b_all, bbB))));
      const float zA = sigm(gA);                    // r0:i0 r1:i1 r2:f0 r3:f1
      const float zB = fmaf(sigm(gB), m1, a1);      // r0:g0 r1:g1 r2:o0 r3:o1
      const float ig1 = zA * zB;                    // r0: i0*g0, r1: i1*g1
      const float fm = shx(zA, 32);                 // r0<-f0, r1<-f1
      c1 = fmaf(fm, c1, ig1);                       // r0: c1a, r1: c1b
      const float th1 = fmaf(2.f, sigm(c1 + c1), -1.f);
      const float om = shx(zB, 32);                 // r0<-o0, r1<-o1
      const float h1v = om * th1;                   // r0: h1a, r1: h1b
      const float t16 = shx(h1v, 16);               // r0<-h1b, r1<-h1a
      // g0 lanes pack (h1a, h1b) for the h1-injection MFMA (B slots e0,e1)
      const unsigned h1p = pkrne(h1v, t16);
      u32x4 b2u; b2u[0] = (g == 0) ? h1p : 0u; b2u[1] = 0u; b2u[2] = 0u; b2u[3] = 0u;
      const f16x8 b2v = __builtin_bit_cast(f16x8, b2u);
      // broadcast h1a,h1b to all rows (needed by next step's LSTM1)
      const float a_c = (g & 1) ? t16 : h1v;        // rows 0,1: h1a
      const float b_c = (g & 1) ? h1v : t16;        // rows 0,1: h1b
      const float a32 = shx(a_c, 32);
      const float b32 = shx(b_c, 32);
      h1a_all = (g & 2) ? a32 : a_c;
      h1b_all = (g & 2) ? b32 : b_c;

      // ---------- (2) h1-injection MFMA (chained into d) ----------
      d0 = __builtin_amdgcn_mfma_f32_16x16x32_f16(a2f[0], b2v, d0, 0, 0, 0);
      d1 = __builtin_amdgcn_mfma_f32_16x16x32_f16(a2f[1], b2v, d1, 0, 0, 0);
      d2 = __builtin_amdgcn_mfma_f32_16x16x32_f16(a2f[2], b2v, d2, 0, 0, 0);
      d3 = __builtin_amdgcn_mfma_f32_16x16x32_f16(a2f[3], b2v, d3, 0, 0, 0);

      // ---------- LSTM2 activations + cell (lane-local, 4 units) ----------
      float h2l[4];
      #pragma unroll
      for (int j = 0; j < 4; ++j){
        const float ii = sigm(d0[j]);
        const float ff = sigm(d1[j]);
        const float gg = fmaf(2.f, sigm(d2[j]), -1.f);
        const float oo = sigm(d3[j]);
        c2[j] = fmaf(ff, c2[j], ii * gg);
        const float th = fmaf(2.f, sigm(c2[j] + c2[j]), -1.f);
        h2l[j] = oo * th;
      }
      pAu = pkrne(h2l[0], h2l[1]);
      pBu = pkrne(h2l[2], h2l[3]);

      // ---------- (3) LSTM3 gate matvec via MFMA ----------
      u32x4 b3u; b3u[0] = pAu; b3u[1] = pBu; b3u[2] = 0u; b3u[3] = 0u;
      const f16x8 b3v = __builtin_bit_cast(f16x8, b3u);
      const f32x4 d3v = __builtin_amdgcn_mfma_f32_16x16x32_f16(a3f, b3v, c3v, 0, 0, 0);
      const float P = fmaf(wh3own, h3_all, d3v[0]); // gate g pre-activation
      const float z  = fmaf(sigm(P), m3, a3);       // r0:i r1:f r2:g r3:o
      const float gvv = shx(z, 32);                 // r0<-g-val, r1<-o
      const float ig3 = z * gvv;                    // r0: i*g
      const float fv = shx(z, 16);                  // r0<-f
      c3 = fmaf(fv, c3, ig3);                       // r0: c3
      const float th3 = fmaf(2.f, sigm(c3 + c3), -1.f);
      const float ov3 = shx(gvv, 16);               // r0<-o
      const float h3v = ov3 * th3;                  // r0: h3
      const float u16 = shx(h3v, 16);
      const float selh = (g & 1) ? u16 : h3v;       // rows 0,1: h3
      const float u32v = shx(selh, 32);
      h3_all = (g & 2) ? u32v : selh;               // all rows: h3
      const float yv = fmaf(wl, h3_all, bl);

      if      (s == 0) o0 = cap ? yv : o0;
      else if (s == 1) o1 = cap ? yv : o1;
      else if (s == 2) o2 = cap ? yv : o2;
      else             o3 = cap ? yv : o3;
    }

    // every 16 steps: all 64 lanes store -> each seq's 64B line fully written
    if ((ch & 3) == 3){
      float4 o4; o4.x = o0; o4.y = o1; o4.z = o2; o4.w = o3;
      *(float4*)(orow + (ch >> 2) * 16 + 4 * g) = o4;
    }
  }
}

extern "C" void kernel_launch(void* const* d_in, const int* in_sizes, int n_in,
                              void* d_out, int out_size, void* d_ws, size_t ws_size,
                              hipStream_t stream)
{
  const float* x     = (const float*)d_in[0];
  const float* w_ih1 = (const float*)d_in[1];
  const float* w_hh1 = (const float*)d_in[2];
  const float* b_ih1 = (const float*)d_in[3];
  const float* b_hh1 = (const float*)d_in[4];
  const float* w_ih2 = (const float*)d_in[5];
  const float* w_hh2 = (const float*)d_in[6];
  const float* b_ih2 = (const float*)d_in[7];
  const float* b_hh2 = (const float*)d_in[8];
  const float* w_ih3 = (const float*)d_in[9];
  const float* w_hh3 = (const float*)d_in[10];
  const float* b_ih3 = (const float*)d_in[11];
  const float* b_hh3 = (const float*)d_in[12];
  const float* w_lin = (const float*)d_in[13];
  const float* b_lin = (const float*)d_in[14];
  float* out = (float*)d_out;

  const int T = 2048;
  const int B = in_sizes[0] / (2 * T);     // 16384
  const int waves   = B / 16;              // 1024 (16 seqs per wave)
  const int blocks  = waves / 4;           // 256 blocks of 256 threads

  lstm3_kernel<<<blocks, 256, 0, stream>>>(
      x, w_ih1, w_hh1, b_ih1, b_hh1,
      w_ih2, w_hh2, b_ih2, b_hh2,
      w_ih3, w_hh3, b_ih3, b_hh3,
      w_lin, b_lin, out, T);
}

// Round 10
// 1060.141 us; speedup vs baseline: 2.7279x; 1.1407x over previous
//
#include <hip/hip_runtime.h>

typedef _Float16 f16x8 __attribute__((ext_vector_type(8)));
typedef float    f32x4 __attribute__((ext_vector_type(4)));
typedef unsigned u32x4 __attribute__((ext_vector_type(4)));

#define DEV __device__ __forceinline__

DEV float fexp2(float x){ return __builtin_amdgcn_exp2f(x); }
DEV float frcp (float x){ return __builtin_amdgcn_rcpf(x); }

// Pre-scaled sigmoid: p already multiplied by -log2(e) (folded into weights).
DEV float sgm(float p){ return frcp(1.0f + fexp2(p)); }
// tanh(c) for ORIGINAL-domain c: exp2(-2*log2e*c), one mul.
DEV float tnc(float c){ return fmaf(2.f, sgm(c * -2.88539008177792682f), -1.f); }

// cross-lane via __shfl_xor ONLY (validated R8)
DEV float shx(float v, int m){ return __shfl_xor(v, m, 64); }

// RNE f16 pack
DEV unsigned pkrne(float a, float b){
  unsigned short ha = __builtin_bit_cast(unsigned short, (_Float16)a);
  unsigned short hb = __builtin_bit_cast(unsigned short, (_Float16)b);
  return (unsigned)ha | ((unsigned)hb << 16);
}

#define L2E_N  (-1.44269504088896341f)
#define L2E2_N (-2.88539008177792682f)

// 16 seqs/wave. Lane l: n=l&15 (seq col, also its A-row), g=l>>4 (k-group).
// Shared A/B labeling k=4g+e, slots e<4 only (validated R7/R8); e>=4 zero.
// Per step (software-pipelined):
//   d_pre (carried) = mfma(A_hh2, B_h2prev, bias)        [issued prev iter]
//   d  = mfma(A_ih2, B_h1, d_pre)                        [h1 inject, g0 e0/e1]
//   ... acts -> h2 -> pack -> issue next d_pre ...
//   pre3 = mfma(A_ih3[row=gate(n&3)], B_h2new, bias3)    -> lane-local LSTM3
// All pre-activation weights/biases pre-scaled by -log2e (tanh rows -2log2e).
__global__ __launch_bounds__(256, 1)
void lstm3_kernel(const float* __restrict__ x,
                  const float* __restrict__ w_ih1, const float* __restrict__ w_hh1,
                  const float* __restrict__ b_ih1, const float* __restrict__ b_hh1,
                  const float* __restrict__ w_ih2, const float* __restrict__ w_hh2,
                  const float* __restrict__ b_ih2, const float* __restrict__ b_hh2,
                  const float* __restrict__ w_ih3, const float* __restrict__ w_hh3,
                  const float* __restrict__ b_ih3, const float* __restrict__ b_hh3,
                  const float* __restrict__ w_lin, const float* __restrict__ b_lin,
                  float* __restrict__ out, int T)
{
  const int tid = threadIdx.x;
  const int l   = tid & 63;
  const int n   = l & 15;
  const int g   = l >> 4;
  const int wv  = tid >> 6;
  const int seq = 16 * (blockIdx.x * 4 + wv) + n;

  // ---------------- LSTM1 (pre-scaled): rows g (i/f) and 4+g (g-gate/o) ----------------
  const int rA = g, rB = 4 + g;
  const float sAq = L2E_N;
  const float sBq = (g < 2) ? L2E2_N : L2E_N;       // rows 4,5 = g-gate
  const float m1  = (g < 2) ? 2.0f : 1.0f;
  const float a1  = (g < 2) ? -1.0f : 0.0f;
  const float w1ax = w_ih1[2*rA]*sAq,  w1ay = w_ih1[2*rA+1]*sAq;
  const float w1ah0 = w_hh1[2*rA]*sAq, w1ah1 = w_hh1[2*rA+1]*sAq;
  const float bbA  = (b_ih1[rA] + b_hh1[rA]) * sAq;
  const float w1bx = w_ih1[2*rB]*sBq,  w1by = w_ih1[2*rB+1]*sBq;
  const float w1bh0 = w_hh1[2*rB]*sBq, w1bh1 = w_hh1[2*rB+1]*sBq;
  const float bbB  = (b_ih1[rB] + b_hh1[rB]) * sBq;

  // ---------------- LSTM2: A fragments (pre-scaled) ----------------
  f16x8 af[4];   // w_hh2, slots e<4 = k 4g+e
  f16x8 a2f[4];  // w_ih2, g0 slots e0/e1
  f32x4 cb[4];
  #pragma unroll
  for (int t = 0; t < 4; ++t){
    const float sc = (t == 2) ? L2E2_N : L2E_N;
    #pragma unroll
    for (int e = 0; e < 8; ++e){
      float v = 0.0f;
      if (e < 4) v = w_hh2[(16*t + n)*16 + (4*g + e)];
      af[t][e] = (_Float16)(v * sc);
      float v2 = 0.0f;
      if (g == 0 && e < 2) v2 = w_ih2[(16*t + n)*2 + e];
      a2f[t][e] = (_Float16)(v2 * sc);
    }
    #pragma unroll
    for (int j = 0; j < 4; ++j){
      const int r = 16*t + 4*g + j;
      cb[t][j] = (b_ih2[r] + b_hh2[r]) * sc;
    }
  }

  // ---------------- LSTM3 lane-local: A row n = w_ih3 gate (n&3) ----------------
  const float s3n = ((n & 3) == 2) ? L2E2_N : L2E_N;
  f16x8 a3f;
  #pragma unroll
  for (int e = 0; e < 8; ++e){
    float v = 0.0f;
    if (e < 4) v = w_ih3[16*(n & 3) + 4*g + e] * s3n;
    a3f[e] = (_Float16)v;
  }
  f32x4 c3v;
  float wh3s0, wh3s1, wh3s2, wh3s3;
  {
    const float s0 = L2E_N, s1 = L2E_N, s2 = L2E2_N, s3_ = L2E_N;
    c3v[0] = (b_ih3[0] + b_hh3[0]) * s0;
    c3v[1] = (b_ih3[1] + b_hh3[1]) * s1;
    c3v[2] = (b_ih3[2] + b_hh3[2]) * s2;
    c3v[3] = (b_ih3[3] + b_hh3[3]) * s3_;
    wh3s0 = w_hh3[0] * s0; wh3s1 = w_hh3[1] * s1;
    wh3s2 = w_hh3[2] * s2; wh3s3 = w_hh3[3] * s3_;
  }
  const float wl = w_lin[0], bl = b_lin[0];

  // ---------------- state ----------------
  float c1 = 0.f, c3 = 0.f;
  float c2[4] = {0.f, 0.f, 0.f, 0.f};
  float h1a_all = 0.f, h1b_all = 0.f, h3 = 0.f;
  unsigned pAu = 0u, pBu = 0u;

  const float* xrow = x + (size_t)seq * (size_t)(2*T);
  float*       orow = out + (size_t)seq * (size_t)T;

  float4 pa = *(const float4*)(xrow);
  float4 pb = *(const float4*)(xrow + 4);

  float o0 = 0.f, o1 = 0.f, o2 = 0.f, o3 = 0.f;

  // prologue: d_pre for step 0 (h2_prev = 0 -> d_pre = bias)
  f32x4 dp0, dp1, dp2, dp3;
  {
    u32x4 bu; bu[0] = 0u; bu[1] = 0u; bu[2] = 0u; bu[3] = 0u;
    const f16x8 bv = __builtin_bit_cast(f16x8, bu);
    dp0 = __builtin_amdgcn_mfma_f32_16x16x32_f16(af[0], bv, cb[0], 0, 0, 0);
    dp1 = __builtin_amdgcn_mfma_f32_16x16x32_f16(af[1], bv, cb[1], 0, 0, 0);
    dp2 = __builtin_amdgcn_mfma_f32_16x16x32_f16(af[2], bv, cb[2], 0, 0, 0);
    dp3 = __builtin_amdgcn_mfma_f32_16x16x32_f16(af[3], bv, cb[3], 0, 0, 0);
  }

  const int NCH = T / 4;
  for (int ch = 0; ch < NCH; ++ch){
    const float4 ca = pa, cbv = pb;
    const int no = (ch + 1 < NCH) ? (ch + 1) * 8 : 0;
    pa = *(const float4*)(xrow + no);
    pb = *(const float4*)(xrow + no + 4);

    const bool cap = (g == (ch & 3));

    #pragma unroll
    for (int s = 0; s < 4; ++s){
      const float x0 = (s==0)?ca.x:(s==1)?ca.z:(s==2)?cbv.x:cbv.z;
      const float x1 = (s==0)?ca.y:(s==1)?ca.w:(s==2)?cbv.y:cbv.w;

      // ---------- LSTM1 ----------
      const float gA = fmaf(w1ax, x0, fmaf(w1ay, x1,
                       fmaf(w1ah0, h1a_all, fmaf(w1ah1, h1b_all, bbA))));
      const float gB = fmaf(w1bx, x0, fmaf(w1by, x1,
                       fmaf(w1bh0, h1a_all, fmaf(w1bh1, h1b_all, bbB))));
      const float zA = sgm(gA);                     // r0:i0 r1:i1 r2:f0 r3:f1
      const float zB = fmaf(sgm(gB), m1, a1);       // r0:g0 r1:g1 r2:o0 r3:o1
      const float ig1 = zA * zB;
      const float fm = shx(zA, 32);
      c1 = fmaf(fm, c1, ig1);
      const float th1 = tnc(c1);
      const float om = shx(zB, 32);
      const float h1v = om * th1;                   // r0: h1a, r1: h1b
      const float t16 = shx(h1v, 16);
      const unsigned h1p = pkrne(h1v, t16);         // g0 lanes: (h1a,h1b)
      u32x4 b2u; b2u[0] = (g == 0) ? h1p : 0u; b2u[1] = 0u; b2u[2] = 0u; b2u[3] = 0u;
      const f16x8 b2v = __builtin_bit_cast(f16x8, b2u);
      const float a_c = (g & 1) ? t16 : h1v;
      const float b_c = (g & 1) ? h1v : t16;
      const float a32 = shx(a_c, 32);
      const float b32 = shx(b_c, 32);
      h1a_all = (g & 2) ? a32 : a_c;
      h1b_all = (g & 2) ? b32 : b_c;

      // ---------- h1-injection MFMA (chains onto carried d_pre) ----------
      const f32x4 d0 = __builtin_amdgcn_mfma_f32_16x16x32_f16(a2f[0], b2v, dp0, 0, 0, 0);
      const f32x4 d1 = __builtin_amdgcn_mfma_f32_16x16x32_f16(a2f[1], b2v, dp1, 0, 0, 0);
      const f32x4 d2 = __builtin_amdgcn_mfma_f32_16x16x32_f16(a2f[2], b2v, dp2, 0, 0, 0);
      const f32x4 d3 = __builtin_amdgcn_mfma_f32_16x16x32_f16(a2f[3], b2v, dp3, 0, 0, 0);

      // ---------- LSTM2 activations + cell ----------
      float h2l[4];
      #pragma unroll
      for (int j = 0; j < 4; ++j){
        const float ii = sgm(d0[j]);
        const float ff = sgm(d1[j]);
        const float gg = fmaf(2.f, sgm(d2[j]), -1.f);
        const float oo = sgm(d3[j]);
        c2[j] = fmaf(ff, c2[j], ii * gg);
        h2l[j] = oo * tnc(c2[j]);
      }
      pAu = pkrne(h2l[0], h2l[1]);
      pBu = pkrne(h2l[2], h2l[3]);

      // ---------- issue NEXT step's h2-recurrence MFMA now ----------
      u32x4 bu; bu[0] = pAu; bu[1] = pBu; bu[2] = 0u; bu[3] = 0u;
      const f16x8 bv = __builtin_bit_cast(f16x8, bu);
      dp0 = __builtin_amdgcn_mfma_f32_16x16x32_f16(af[0], bv, cb[0], 0, 0, 0);
      dp1 = __builtin_amdgcn_mfma_f32_16x16x32_f16(af[1], bv, cb[1], 0, 0, 0);
      dp2 = __builtin_amdgcn_mfma_f32_16x16x32_f16(af[2], bv, cb[2], 0, 0, 0);
      dp3 = __builtin_amdgcn_mfma_f32_16x16x32_f16(af[3], bv, cb[3], 0, 0, 0);

      // ---------- LSTM3: lane-local (all 4 gates in d3v) ----------
      const f32x4 d3v = __builtin_amdgcn_mfma_f32_16x16x32_f16(a3f, bv, c3v, 0, 0, 0);
      const float p_i = fmaf(wh3s0, h3, d3v[0]);
      const float p_f = fmaf(wh3s1, h3, d3v[1]);
      const float p_g = fmaf(wh3s2, h3, d3v[2]);
      const float p_o = fmaf(wh3s3, h3, d3v[3]);
      const float i3 = sgm(p_i);
      const float f3 = sgm(p_f);
      const float g3 = fmaf(2.f, sgm(p_g), -1.f);
      const float q3 = sgm(p_o);
      c3 = fmaf(f3, c3, i3 * g3);
      h3 = q3 * tnc(c3);
      const float yv = fmaf(wl, h3, bl);

      if      (s == 0) o0 = cap ? yv : o0;
      else if (s == 1) o1 = cap ? yv : o1;
      else if (s == 2) o2 = cap ? yv : o2;
      else             o3 = cap ? yv : o3;
    }

    if ((ch & 3) == 3){
      float4 o4; o4.x = o0; o4.y = o1; o4.z = o2; o4.w = o3;
      *(float4*)(orow + (ch >> 2) * 16 + 4 * g) = o4;
    }
  }
}

extern "C" void kernel_launch(void* const* d_in, const int* in_sizes, int n_in,
                              void* d_out, int out_size, void* d_ws, size_t ws_size,
                              hipStream_t stream)
{
  const float* x     = (const float*)d_in[0];
  const float* w_ih1 = (const float*)d_in[1];
  const float* w_hh1 = (const float*)d_in[2];
  const float* b_ih1 = (const float*)d_in[3];
  const float* b_hh1 = (const float*)d_in[4];
  const float* w_ih2 = (const float*)d_in[5];
  const float* w_hh2 = (const float*)d_in[6];
  const float* b_ih2 = (const float*)d_in[7];
  const float* b_hh2 = (const float*)d_in[8];
  const float* w_ih3 = (const float*)d_in[9];
  const float* w_hh3 = (const float*)d_in[10];
  const float* b_ih3 = (const float*)d_in[11];
  const float* b_hh3 = (const float*)d_in[12];
  const float* w_lin = (const float*)d_in[13];
  const float* b_lin = (const float*)d_in[14];
  float* out = (float*)d_out;

  const int T = 2048;
  const int B = in_sizes[0] / (2 * T);     // 16384
  const int waves   = B / 16;              // 1024
  const int blocks  = waves / 4;           // 256

  lstm3_kernel<<<blocks, 256, 0, stream>>>(
      x, w_ih1, w_hh1, b_ih1, b_hh1,
      w_ih2, w_hh2, b_ih2, b_hh2,
      w_ih3, w_hh3, b_ih3, b_hh3,
      w_lin, b_lin, out, T);
}